// Round 7
// baseline (1704.941 us; speedup 1.0000x reference)
//
#include <hip/hip_runtime.h>
#include <math.h>

// Problem constants
#define B_TOT   2048
#define N_IN    1024
#define N_H     1024
#define N_OUT   512
#define N_UPD   1536
#define T_TOT   3072   // MAX_STEPS * N_UPD
#define N_WIN   48     // T_TOT / 64

// ---------------- prep kernels ----------------

// W1T[c*1024 + r] = W1[r*1024 + c]
__global__ void prep_w1t(const float* __restrict__ W1, float* __restrict__ W1T) {
    int idx = blockIdx.x * 256 + threadIdx.x;   // < 1024*1024
    int r = idx & 1023;
    int c = idx >> 10;
    W1T[(size_t)c * 1024 + r] = W1[(size_t)r * 1024 + c];
}

// W2Tf[c*512 + r] = W2[r*1024 + c]
__global__ void prep_w2tf(const float* __restrict__ W2, float* __restrict__ W2Tf) {
    int idx = blockIdx.x * 256 + threadIdx.x;   // < 512*1024
    int r = idx & 511;
    int c = idx >> 9;
    W2Tf[(size_t)c * 512 + r] = W2[(size_t)r * 1024 + c];
}

// WHf[n][lane][j] = W2[(j*64+lane)][n]   (hidden-flip fragment: h2 coupling, 8F/lane)
__global__ void prep_whf(const float* __restrict__ W2, float* __restrict__ WHf) {
    int idx = blockIdx.x * 256 + threadIdx.x;   // < 1024*512
    int n = idx >> 9;
    int r = idx & 511;
    int l = r >> 3, j = r & 7;
    WHf[idx] = W2[(size_t)(j * 64 + l) * 1024 + n];
}

// WOf[nn][lane][j] = W2[nn][j*64+lane]   (output-flip fragment: h1 coupling, 16F/lane)
__global__ void prep_wof(const float* __restrict__ W2, float* __restrict__ WOf) {
    int idx = blockIdx.x * 256 + threadIdx.x;   // < 512*1024
    int nn = idx >> 10;
    int r = idx & 1023;
    int l = r >> 4, j = r & 15;
    WOf[idx] = W2[(size_t)nn * 1024 + j * 64 + l];
}

// WXf[w][j][l]: fp32 coupling of flip at step w*64+j onto decision at step w*64+l.
__global__ void prep_wx(const float* __restrict__ W2, const int* __restrict__ ids,
                        float* __restrict__ WXf) {
    int idx = blockIdx.x * 256 + threadIdx.x;   // < 48*4096
    int w = idx >> 12;
    int j = (idx >> 6) & 63;
    int l = idx & 63;
    int mj = ids[w * 64 + j];
    int nl = ids[w * 64 + l];
    float v = 0.0f;
    if (mj < N_H && nl >= N_H) v = W2[(size_t)(nl - N_H) * 1024 + mj];
    else if (mj >= N_H && nl < N_H) v = W2[(size_t)(mj - N_H) * 1024 + nl];
    WXf[idx] = v;
}

// posA[n] = sweep-1 step of unit n; posB[n] = sweep-2 step - 1536
__global__ void prep_pos(const int* __restrict__ ids, int* __restrict__ posA,
                         int* __restrict__ posB) {
    int t = blockIdx.x * 256 + threadIdx.x;   // < 3072
    int n = ids[t];
    if (t < N_UPD) posA[n] = t; else posB[n] = t - N_UPD;
}

// pos2[t] = posA[ids[1536 + t]]
__global__ void prep_pos2(const int* __restrict__ ids, const int* __restrict__ posA,
                          int* __restrict__ pos2) {
    int t = blockIdx.x * 256 + threadIdx.x;   // < 1536
    pos2[t] = posA[ids[N_UPD + t]];
}

// TH[b][t] = T(t) * logit(u[t][b])  in fp64 (tiled transpose; same formula as before)
__global__ __launch_bounds__(256) void prep_th(const float* __restrict__ u,
                                               double* __restrict__ TH) {
    __shared__ double tile[64][65];
    int bt = blockIdx.x % 48;   // t tile
    int bb = blockIdx.x / 48;   // b tile
    int tx = threadIdx.x & 63;
    int ty0 = threadIdx.x >> 6;
    const double T1c = (double)(float)(2.0 / exp((double)1 / 5.0));
    for (int r = ty0; r < 64; r += 4) {
        int t = bt * 64 + r;
        float uv = u[(size_t)t * 2048 + bb * 64 + tx];
        double T = (t >= N_UPD) ? T1c : 2.0;
        double ud = (double)uv;
        tile[r][tx] = T * (log(ud) - log1p(-ud));
    }
    __syncthreads();
    for (int r = ty0; r < 64; r += 4)
        TH[(size_t)(bb * 64 + r) * 3072 + bt * 64 + tx] = tile[tx][r];
}

// out[b][0:1024] = x[b][:]
__global__ void copy_x(const float* __restrict__ x, float* __restrict__ out) {
    int idx = blockIdx.x * 256 + threadIdx.x;   // < 2048*256 (float4 units)
    int b = idx >> 8, c = idx & 255;
    ((float4*)(out + (size_t)b * 2560))[c] = ((const float4*)(x + (size_t)b * 1024))[c];
}

// ---------------- init fields (fp64, per-row add order unchanged) ----------------
// ONE batch row per block -> 2048 blocks.
__global__ __launch_bounds__(256) void init_fields(
    const float* __restrict__ x, const float* __restrict__ s1i, const float* __restrict__ s2i,
    const float* __restrict__ W1T, const float* __restrict__ W2, const float* __restrict__ W2Tf,
    const float* __restrict__ b1, const float* __restrict__ b2,
    double* __restrict__ h1g, double* __restrict__ h2g)
{
    const int tid = threadIdx.x;
    const int b0 = blockIdx.x;

    __shared__ unsigned char xm[1024];
    __shared__ unsigned char s2msk[512];
    __shared__ unsigned char s1msk[1024];

    for (int i = tid; i < 1024; i += 256)
        xm[i] = (x[(size_t)b0 * 1024 + i] != 0.0f) ? 1 : 0;
    for (int j = tid; j < 512; j += 256)
        s2msk[j] = (s2i[(size_t)b0 * 512 + j] != 0.0f) ? 1 : 0;
    for (int j = tid; j < 1024; j += 256)
        s1msk[j] = (s1i[(size_t)b0 * 1024 + j] != 0.0f) ? 1 : 0;
    __syncthreads();

    double h1r[4];
    #pragma unroll
    for (int k = 0; k < 4; ++k) h1r[k] = (double)b1[k * 256 + tid];
    double h2r[2];
    #pragma unroll
    for (int k = 0; k < 2; ++k) h2r[k] = (double)b2[k * 256 + tid];

    // part 1: x @ W1^T
    {
        const unsigned* xmu = (const unsigned*)xm;
        unsigned mwn = xmu[0];
        float wc[16];
        #pragma unroll
        for (int s = 0; s < 4; ++s) {
            const float* q = W1T + (size_t)s * 1024 + tid;
            wc[s*4+0] = q[0]; wc[s*4+1] = q[256]; wc[s*4+2] = q[512]; wc[s*4+3] = q[768];
        }
        for (int g = 0; g < 256; ++g) {
            unsigned mg = (unsigned)__builtin_amdgcn_readfirstlane((int)mwn);
            if (g + 1 < 256) mwn = xmu[g + 1];
            float wn[16];
            if (g + 1 < 256) {
                #pragma unroll
                for (int s = 0; s < 4; ++s) {
                    const float* q = W1T + (size_t)(4 * (g + 1) + s) * 1024 + tid;
                    wn[s*4+0] = q[0]; wn[s*4+1] = q[256]; wn[s*4+2] = q[512]; wn[s*4+3] = q[768];
                }
            } else {
                #pragma unroll
                for (int z = 0; z < 16; ++z) wn[z] = wc[z];
            }
            #pragma unroll
            for (int s = 0; s < 4; ++s) {
                if ((mg >> (8 * s)) & 1u) {
                    h1r[0] += (double)wc[s*4+0]; h1r[1] += (double)wc[s*4+1];
                    h1r[2] += (double)wc[s*4+2]; h1r[3] += (double)wc[s*4+3];
                }
            }
            #pragma unroll
            for (int z = 0; z < 16; ++z) wc[z] = wn[z];
        }
    }
    // part 2: s2 @ W2
    {
        const unsigned* s2u = (const unsigned*)s2msk;
        unsigned mwn = s2u[0];
        float wc[16];
        #pragma unroll
        for (int s = 0; s < 4; ++s) {
            const float* q = W2 + (size_t)s * 1024 + tid;
            wc[s*4+0] = q[0]; wc[s*4+1] = q[256]; wc[s*4+2] = q[512]; wc[s*4+3] = q[768];
        }
        for (int g = 0; g < 128; ++g) {
            unsigned mg = (unsigned)__builtin_amdgcn_readfirstlane((int)mwn);
            if (g + 1 < 128) mwn = s2u[g + 1];
            float wn[16];
            if (g + 1 < 128) {
                #pragma unroll
                for (int s = 0; s < 4; ++s) {
                    const float* q = W2 + (size_t)(4 * (g + 1) + s) * 1024 + tid;
                    wn[s*4+0] = q[0]; wn[s*4+1] = q[256]; wn[s*4+2] = q[512]; wn[s*4+3] = q[768];
                }
            } else {
                #pragma unroll
                for (int z = 0; z < 16; ++z) wn[z] = wc[z];
            }
            #pragma unroll
            for (int s = 0; s < 4; ++s) {
                if ((mg >> (8 * s)) & 1u) {
                    h1r[0] += (double)wc[s*4+0]; h1r[1] += (double)wc[s*4+1];
                    h1r[2] += (double)wc[s*4+2]; h1r[3] += (double)wc[s*4+3];
                }
            }
            #pragma unroll
            for (int z = 0; z < 16; ++z) wc[z] = wn[z];
        }
    }
    // part 3: s1 @ W2^T
    {
        const unsigned* s1u = (const unsigned*)s1msk;
        unsigned mwn = s1u[0];
        float wc[8];
        #pragma unroll
        for (int s = 0; s < 4; ++s) {
            const float* q = W2Tf + (size_t)s * 512 + tid;
            wc[s*2+0] = q[0]; wc[s*2+1] = q[256];
        }
        for (int g = 0; g < 256; ++g) {
            unsigned mg = (unsigned)__builtin_amdgcn_readfirstlane((int)mwn);
            if (g + 1 < 256) mwn = s1u[g + 1];
            float wn[8];
            if (g + 1 < 256) {
                #pragma unroll
                for (int s = 0; s < 4; ++s) {
                    const float* q = W2Tf + (size_t)(4 * (g + 1) + s) * 512 + tid;
                    wn[s*2+0] = q[0]; wn[s*2+1] = q[256];
                }
            } else {
                #pragma unroll
                for (int z = 0; z < 8; ++z) wn[z] = wc[z];
            }
            #pragma unroll
            for (int s = 0; s < 4; ++s) {
                if ((mg >> (8 * s)) & 1u) {
                    h2r[0] += (double)wc[s*2+0]; h2r[1] += (double)wc[s*2+1];
                }
            }
            #pragma unroll
            for (int z = 0; z < 8; ++z) wc[z] = wn[z];
        }
    }

    #pragma unroll
    for (int k = 0; k < 4; ++k) h1g[(size_t)b0 * 1024 + k * 256 + tid] = h1r[k];
    #pragma unroll
    for (int k = 0; k < 2; ++k) h2g[(size_t)b0 * 512 + k * 256 + tid] = h2r[k];
}

// ---------------- Gibbs chain: 2 waves per batch row ----------------
// wave0 owns h1 (hidden fields, 16 f64/lane); wave1 owns h2 (8 f64/lane).
// Both waves run the identical serial decision loop (bitwise-identical A);
// wave0 applies output-unit flips (to h1), wave1 hidden flips (to h2).
// __launch_bounds__(128,2): generous VGPR cap (256) so the allocator never
// spills to scratch (round-6 regression: (128,4) -> 64-VGPR alloc + 596 MB
// scratch traffic). Occupancy comes from actual usage (~110 VGPR -> 4/SIMD).

__global__ __launch_bounds__(128, 2) void gibbs(
    const double* __restrict__ TH, const int* __restrict__ ids,
    const float* __restrict__ WHf, const float* __restrict__ WOf,
    const float* __restrict__ WXf,
    const int* __restrict__ pos2, const int* __restrict__ posB,
    const double* __restrict__ h1g, const double* __restrict__ h2g,
    const float* __restrict__ s1i, const float* __restrict__ s2i,
    float* __restrict__ out)
{
    const int lane = threadIdx.x & 63;
    const int wid  = threadIdx.x >> 6;     // 0: h1-owner, 1: h2-owner
    const int b = blockIdx.x;

    __shared__ double fld[1536];
    __shared__ unsigned long long act[N_WIN];
    __shared__ unsigned long long sb[24];

    double hr[16];
    if (wid == 0) {
        #pragma unroll
        for (int k = 0; k < 16; ++k) hr[k] = h1g[(size_t)b * 1024 + k * 64 + lane];
        #pragma unroll
        for (int k = 0; k < 16; ++k) {
            unsigned long long m = __ballot(s1i[(size_t)b * 1024 + k * 64 + lane] != 0.0f);
            if (lane == 0) sb[k] = m;
        }
    } else {
        #pragma unroll
        for (int k = 0; k < 8; ++k) hr[k] = h2g[(size_t)b * 512 + k * 64 + lane];
        #pragma unroll
        for (int k = 0; k < 8; ++k) {
            unsigned long long m = __ballot(s2i[(size_t)b * 512 + k * 64 + lane] != 0.0f);
            if (lane == 0) sb[16 + k] = m;
        }
    }

    int idw = ids[lane];
    double thc = TH[(size_t)b * 3072 + lane];
    int p2c = 0;

    for (int w = 0; w < N_WIN; ++w) {
        const int t0 = w * 64;

        // mirror own fields to LDS
        if (wid == 0) {
            #pragma unroll
            for (int k = 0; k < 16; ++k) fld[k * 64 + lane] = hr[k];
        } else {
            #pragma unroll
            for (int k = 0; k < 8; ++k) fld[1024 + k * 64 + lane] = hr[k];
        }
        __syncthreads();
        double g = fld[idw];
        __syncthreads();    // fld free for next window after both waves gathered

        // old state (identical in both waves)
        int oldb;
        if (w < 24) {
            unsigned long long sv = sb[idw >> 6];
            oldb = (int)((sv >> (idw & 63)) & 1ull);
        } else {
            unsigned long long av = act[p2c >> 6];
            oldb = (int)((av >> (p2c & 63)) & 1ull);
        }
        unsigned long long OLD  = __ballot(oldb != 0);
        unsigned long long TYPE = __ballot(idw >= N_H);

        // prefetch next window inputs (consumed next iteration)
        int idn = 0; double thn = 0.0; int p2n = 0;
        if (w + 1 < N_WIN) {
            idn = ids[t0 + 64 + lane];
            thn = TH[(size_t)b * 3072 + t0 + 64 + lane];
            if (w + 1 >= 24) p2n = pos2[(w - 23) * 64 + lane];
        }

        // serial decision loop (identical in both waves), wx depth-8 prefetch
        const float* wxp = WXf + ((size_t)w << 12) + lane;
        double wxd[8];
        #pragma unroll
        for (int j = 0; j < 8; ++j) wxd[j] = (double)wxp[(size_t)j * 64];

        unsigned long long A = 0;
        for (int jo = 0; jo < 64; jo += 8) {
            #pragma unroll
            for (int ji = 0; ji < 8; ++ji) {
                const int j = jo + ji;
                unsigned long long m = __ballot(g > thc);
                int a = (int)((m >> j) & 1ull);
                int o = (int)((OLD >> j) & 1ull);
                A |= ((unsigned long long)a) << j;
                double sd = (a == o) ? 0.0 : (a ? 1.0 : -1.0);
                g = fma(sd, wxd[ji], g);
                if (jo + 8 < 64) wxd[ji] = (double)wxp[(size_t)(j + 8) * 64];
            }
        }
        if (wid == 0 && lane == 0) act[w] = A;

        // apply own-layer flips, depth-2 pipelined row loads
        if (wid == 0) {
            unsigned long long CC = (A ^ OLD) & TYPE;     // output-unit flips -> h1
            int j0 = -1, j1 = -1;
            float4 r00, r01, r02, r03, r10, r11, r12, r13;
            if (CC) {
                j0 = __builtin_ctzll(CC); CC &= CC - 1;
                int n = __builtin_amdgcn_readlane(idw, j0);
                const float4* p = (const float4*)(WOf + ((size_t)(n - N_H) << 10)) + (lane << 2);
                r00 = p[0]; r01 = p[1]; r02 = p[2]; r03 = p[3];
            }
            if (CC) {
                j1 = __builtin_ctzll(CC); CC &= CC - 1;
                int n = __builtin_amdgcn_readlane(idw, j1);
                const float4* p = (const float4*)(WOf + ((size_t)(n - N_H) << 10)) + (lane << 2);
                r10 = p[0]; r11 = p[1]; r12 = p[2]; r13 = p[3];
            }
            while (j0 >= 0) {
                double sd = ((A >> j0) & 1ull) ? 1.0 : -1.0;
                hr[0]  = fma(sd, (double)r00.x, hr[0]);
                hr[1]  = fma(sd, (double)r00.y, hr[1]);
                hr[2]  = fma(sd, (double)r00.z, hr[2]);
                hr[3]  = fma(sd, (double)r00.w, hr[3]);
                hr[4]  = fma(sd, (double)r01.x, hr[4]);
                hr[5]  = fma(sd, (double)r01.y, hr[5]);
                hr[6]  = fma(sd, (double)r01.z, hr[6]);
                hr[7]  = fma(sd, (double)r01.w, hr[7]);
                hr[8]  = fma(sd, (double)r02.x, hr[8]);
                hr[9]  = fma(sd, (double)r02.y, hr[9]);
                hr[10] = fma(sd, (double)r02.z, hr[10]);
                hr[11] = fma(sd, (double)r02.w, hr[11]);
                hr[12] = fma(sd, (double)r03.x, hr[12]);
                hr[13] = fma(sd, (double)r03.y, hr[13]);
                hr[14] = fma(sd, (double)r03.z, hr[14]);
                hr[15] = fma(sd, (double)r03.w, hr[15]);
                j0 = j1; r00 = r10; r01 = r11; r02 = r12; r03 = r13;
                j1 = -1;
                if (CC) {
                    j1 = __builtin_ctzll(CC); CC &= CC - 1;
                    int n = __builtin_amdgcn_readlane(idw, j1);
                    const float4* p = (const float4*)(WOf + ((size_t)(n - N_H) << 10)) + (lane << 2);
                    r10 = p[0]; r11 = p[1]; r12 = p[2]; r13 = p[3];
                }
            }
        } else {
            unsigned long long CC = (A ^ OLD) & ~TYPE;    // hidden-unit flips -> h2
            int j0 = -1, j1 = -1;
            float4 r00, r01, r10, r11;
            if (CC) {
                j0 = __builtin_ctzll(CC); CC &= CC - 1;
                int n = __builtin_amdgcn_readlane(idw, j0);
                const float4* p = (const float4*)(WHf + ((size_t)n << 9)) + (lane << 1);
                r00 = p[0]; r01 = p[1];
            }
            if (CC) {
                j1 = __builtin_ctzll(CC); CC &= CC - 1;
                int n = __builtin_amdgcn_readlane(idw, j1);
                const float4* p = (const float4*)(WHf + ((size_t)n << 9)) + (lane << 1);
                r10 = p[0]; r11 = p[1];
            }
            while (j0 >= 0) {
                double sd = ((A >> j0) & 1ull) ? 1.0 : -1.0;
                hr[0] = fma(sd, (double)r00.x, hr[0]);
                hr[1] = fma(sd, (double)r00.y, hr[1]);
                hr[2] = fma(sd, (double)r00.z, hr[2]);
                hr[3] = fma(sd, (double)r00.w, hr[3]);
                hr[4] = fma(sd, (double)r01.x, hr[4]);
                hr[5] = fma(sd, (double)r01.y, hr[5]);
                hr[6] = fma(sd, (double)r01.z, hr[6]);
                hr[7] = fma(sd, (double)r01.w, hr[7]);
                j0 = j1; r00 = r10; r01 = r11;
                j1 = -1;
                if (CC) {
                    j1 = __builtin_ctzll(CC); CC &= CC - 1;
                    int n = __builtin_amdgcn_readlane(idw, j1);
                    const float4* p = (const float4*)(WHf + ((size_t)n << 9)) + (lane << 1);
                    r10 = p[0]; r11 = p[1];
                }
            }
        }

        idw = idn; thc = thn; p2c = p2n;
    }

    __syncthreads();   // act fully written

    // epilogue: final states = sweep-2 decision bits
    if (wid == 0) {
        #pragma unroll
        for (int k = 0; k < 16; ++k) {
            int p = posB[k * 64 + lane];
            unsigned long long av = act[24 + (p >> 6)];
            out[(size_t)b * 2560 + 1024 + k * 64 + lane] = (float)((av >> (p & 63)) & 1ull);
        }
    } else {
        #pragma unroll
        for (int k = 0; k < 8; ++k) {
            int p = posB[1024 + k * 64 + lane];
            unsigned long long av = act[24 + (p >> 6)];
            out[(size_t)b * 2560 + 2048 + k * 64 + lane] = (float)((av >> (p & 63)) & 1ull);
        }
    }
}

// ---------------- launch ----------------
extern "C" void kernel_launch(void* const* d_in, const int* in_sizes, int n_in,
                              void* d_out, int out_size, void* d_ws, size_t ws_size,
                              hipStream_t stream) {
    const float* x   = (const float*)d_in[0];
    const float* s1i = (const float*)d_in[1];
    const float* s2i = (const float*)d_in[2];
    const float* W1  = (const float*)d_in[3];
    const float* b1  = (const float*)d_in[4];
    const float* W2  = (const float*)d_in[5];
    const float* b2  = (const float*)d_in[6];
    const float* u   = (const float*)d_in[7];
    const int*   ids = (const int*)d_in[8];
    float* out = (float*)d_out;

    char* ws = (char*)d_ws;
    float*  W1T  = (float*) (ws);                               //  4 MB
    float*  W2Tf = (float*) (ws + ((size_t)4  << 20));          //  2 MB
    float*  WHf  = (float*) (ws + ((size_t)6  << 20));          //  2 MB
    float*  WOf  = (float*) (ws + ((size_t)8  << 20));          //  2 MB
    float*  WXf  = (float*) (ws + ((size_t)10 << 20));          //  768 KB
    int*    posA = (int*)   (ws + ((size_t)11 << 20));          //  6 KB
    int*    posB = (int*)   (ws + ((size_t)11 << 20) + 8192);   //  6 KB
    int*    pos2 = (int*)   (ws + ((size_t)11 << 20) + 16384);  //  6 KB
    double* THd  = (double*)(ws + ((size_t)12 << 20));          // 48 MB
    double* h1g  = (double*)(ws + ((size_t)60 << 20));          // 16 MB
    double* h2g  = (double*)(ws + ((size_t)76 << 20));          //  8 MB (total 84 MB)

    hipLaunchKernelGGL(prep_w1t,  dim3(4096), dim3(256), 0, stream, W1, W1T);
    hipLaunchKernelGGL(prep_w2tf, dim3(2048), dim3(256), 0, stream, W2, W2Tf);
    hipLaunchKernelGGL(prep_whf,  dim3(2048), dim3(256), 0, stream, W2, WHf);
    hipLaunchKernelGGL(prep_wof,  dim3(2048), dim3(256), 0, stream, W2, WOf);
    hipLaunchKernelGGL(prep_wx,   dim3(768),  dim3(256), 0, stream, W2, ids, WXf);
    hipLaunchKernelGGL(prep_pos,  dim3(12),   dim3(256), 0, stream, ids, posA, posB);
    hipLaunchKernelGGL(prep_pos2, dim3(6),    dim3(256), 0, stream, ids, posA, pos2);
    hipLaunchKernelGGL(prep_th,   dim3(1536), dim3(256), 0, stream, u, THd);
    hipLaunchKernelGGL(copy_x,    dim3(2048), dim3(256), 0, stream, x, out);
    hipLaunchKernelGGL(init_fields, dim3(2048), dim3(256), 0, stream,
                       x, s1i, s2i, W1T, W2, W2Tf, b1, b2, h1g, h2g);
    hipLaunchKernelGGL(gibbs, dim3(2048), dim3(128), 0, stream,
                       THd, ids, WHf, WOf, WXf, pos2, posB, h1g, h2g, s1i, s2i, out);
}

// Round 8
// 1514.535 us; speedup vs baseline: 1.1257x; 1.1257x over previous
//
#include <hip/hip_runtime.h>
#include <math.h>

// Problem constants
#define B_TOT   2048
#define N_IN    1024
#define N_H     1024
#define N_OUT   512
#define N_UPD   1536
#define T_TOT   3072   // MAX_STEPS * N_UPD
#define N_WIN   48     // T_TOT / 64

// ---------------- prep kernels ----------------

// W1T[c*1024 + r] = W1[r*1024 + c]
__global__ void prep_w1t(const float* __restrict__ W1, float* __restrict__ W1T) {
    int idx = blockIdx.x * 256 + threadIdx.x;   // < 1024*1024
    int r = idx & 1023;
    int c = idx >> 10;
    W1T[(size_t)c * 1024 + r] = W1[(size_t)r * 1024 + c];
}

// W2Tf[c*512 + r] = W2[r*1024 + c]
__global__ void prep_w2tf(const float* __restrict__ W2, float* __restrict__ W2Tf) {
    int idx = blockIdx.x * 256 + threadIdx.x;   // < 512*1024
    int r = idx & 511;
    int c = idx >> 9;
    W2Tf[(size_t)c * 512 + r] = W2[(size_t)r * 1024 + c];
}

// WHf[n][lane][j] = W2[(j*64+lane)][n]   (hidden-flip fragment: h2 coupling, 8F/lane)
__global__ void prep_whf(const float* __restrict__ W2, float* __restrict__ WHf) {
    int idx = blockIdx.x * 256 + threadIdx.x;   // < 1024*512
    int n = idx >> 9;
    int r = idx & 511;
    int l = r >> 3, j = r & 7;
    WHf[idx] = W2[(size_t)(j * 64 + l) * 1024 + n];
}

// WOf[nn][lane][j] = W2[nn][j*64+lane]   (output-flip fragment: h1 coupling, 16F/lane)
__global__ void prep_wof(const float* __restrict__ W2, float* __restrict__ WOf) {
    int idx = blockIdx.x * 256 + threadIdx.x;   // < 512*1024
    int nn = idx >> 10;
    int r = idx & 1023;
    int l = r >> 4, j = r & 15;
    WOf[idx] = W2[(size_t)nn * 1024 + j * 64 + l];
}

// WXT4[w][k][l][c] = coupling of flip at step w*64+(4k+c) onto decision at step w*64+l.
// Laid out so lane l's 16 float4 loads per window are fully coalesced.
__global__ void prep_wxt4(const float* __restrict__ W2, const int* __restrict__ ids,
                          float* __restrict__ WXT4) {
    int idx = blockIdx.x * 256 + threadIdx.x;   // < 48*4096
    int w = idx >> 12;
    int k = (idx >> 8) & 15;
    int l = (idx >> 2) & 63;
    int c = idx & 3;
    int j = 4 * k + c;
    int mj = ids[w * 64 + j];
    int nl = ids[w * 64 + l];
    float v = 0.0f;
    if (mj < N_H && nl >= N_H) v = W2[(size_t)(nl - N_H) * 1024 + mj];
    else if (mj >= N_H && nl < N_H) v = W2[(size_t)(mj - N_H) * 1024 + nl];
    WXT4[idx] = v;
}

// posA[n] = sweep-1 step of unit n; posB[n] = sweep-2 step - 1536
__global__ void prep_pos(const int* __restrict__ ids, int* __restrict__ posA,
                         int* __restrict__ posB) {
    int t = blockIdx.x * 256 + threadIdx.x;   // < 3072
    int n = ids[t];
    if (t < N_UPD) posA[n] = t; else posB[n] = t - N_UPD;
}

// pos2[t] = posA[ids[1536 + t]]
__global__ void prep_pos2(const int* __restrict__ ids, const int* __restrict__ posA,
                          int* __restrict__ pos2) {
    int t = blockIdx.x * 256 + threadIdx.x;   // < 1536
    pos2[t] = posA[ids[N_UPD + t]];
}

// TH[b][t] = T(t) * logit(u[t][b])  in fp64 (tiled transpose; same formula as before)
__global__ __launch_bounds__(256) void prep_th(const float* __restrict__ u,
                                               double* __restrict__ TH) {
    __shared__ double tile[64][65];
    int bt = blockIdx.x % 48;   // t tile
    int bb = blockIdx.x / 48;   // b tile
    int tx = threadIdx.x & 63;
    int ty0 = threadIdx.x >> 6;
    const double T1c = (double)(float)(2.0 / exp((double)1 / 5.0));
    for (int r = ty0; r < 64; r += 4) {
        int t = bt * 64 + r;
        float uv = u[(size_t)t * 2048 + bb * 64 + tx];
        double T = (t >= N_UPD) ? T1c : 2.0;
        double ud = (double)uv;
        tile[r][tx] = T * (log(ud) - log1p(-ud));
    }
    __syncthreads();
    for (int r = ty0; r < 64; r += 4)
        __builtin_nontemporal_store(tile[tx][r],
            &TH[(size_t)(bb * 64 + r) * 3072 + bt * 64 + tx]);
}

// out[b][0:1024] = x[b][:]
__global__ void copy_x(const float* __restrict__ x, float* __restrict__ out) {
    int idx = blockIdx.x * 256 + threadIdx.x;   // < 2048*256 (float4 units)
    int b = idx >> 8, c = idx & 255;
    ((float4*)(out + (size_t)b * 2560))[c] = ((const float4*)(x + (size_t)b * 1024))[c];
}

// ---------------- init fields (fp64, per-accumulator add order unchanged) ----------------
// 8 batch rows per block -> 256 blocks (cuts weight-table L2 traffic 8x vs 1-row).
__global__ __launch_bounds__(256) void init_fields(
    const float* __restrict__ x, const float* __restrict__ s1i, const float* __restrict__ s2i,
    const float* __restrict__ W1T, const float* __restrict__ W2, const float* __restrict__ W2Tf,
    const float* __restrict__ b1, const float* __restrict__ b2,
    double* __restrict__ h1g, double* __restrict__ h2g)
{
    const int tid = threadIdx.x;
    const int b0 = blockIdx.x * 8;

    __shared__ unsigned char xm[1024];
    __shared__ unsigned char s2msk[512];
    __shared__ unsigned char s1msk[1024];

    for (int i = tid; i < 1024; i += 256) {
        unsigned m = 0;
        #pragma unroll
        for (int b = 0; b < 8; ++b) m |= (x[(size_t)(b0 + b) * 1024 + i] != 0.0f) << b;
        xm[i] = (unsigned char)m;
    }
    for (int j = tid; j < 512; j += 256) {
        unsigned m = 0;
        #pragma unroll
        for (int b = 0; b < 8; ++b) m |= (s2i[(size_t)(b0 + b) * 512 + j] != 0.0f) << b;
        s2msk[j] = (unsigned char)m;
    }
    for (int j = tid; j < 1024; j += 256) {
        unsigned m = 0;
        #pragma unroll
        for (int b = 0; b < 8; ++b) m |= (s1i[(size_t)(b0 + b) * 1024 + j] != 0.0f) << b;
        s1msk[j] = (unsigned char)m;
    }
    __syncthreads();

    double h1r[32];   // h1r[k*8+b], m = k*256 + tid
    #pragma unroll
    for (int k = 0; k < 4; ++k) {
        double bv = (double)b1[k * 256 + tid];
        #pragma unroll
        for (int b = 0; b < 8; ++b) h1r[k * 8 + b] = bv;
    }
    double h2r[16];
    #pragma unroll
    for (int k = 0; k < 2; ++k) {
        double bv = (double)b2[k * 256 + tid];
        #pragma unroll
        for (int b = 0; b < 8; ++b) h2r[k * 8 + b] = bv;
    }

    // part 1: x @ W1^T
    {
        const unsigned* xmu = (const unsigned*)xm;
        unsigned mwn = xmu[0];
        float wc[16];
        #pragma unroll
        for (int s = 0; s < 4; ++s) {
            const float* q = W1T + (size_t)s * 1024 + tid;
            wc[s*4+0] = q[0]; wc[s*4+1] = q[256]; wc[s*4+2] = q[512]; wc[s*4+3] = q[768];
        }
        for (int g = 0; g < 256; ++g) {
            unsigned mg = (unsigned)__builtin_amdgcn_readfirstlane((int)mwn);
            if (g + 1 < 256) mwn = xmu[g + 1];
            float wn[16];
            if (g + 1 < 256) {
                #pragma unroll
                for (int s = 0; s < 4; ++s) {
                    const float* q = W1T + (size_t)(4 * (g + 1) + s) * 1024 + tid;
                    wn[s*4+0] = q[0]; wn[s*4+1] = q[256]; wn[s*4+2] = q[512]; wn[s*4+3] = q[768];
                }
            } else {
                #pragma unroll
                for (int z = 0; z < 16; ++z) wn[z] = wc[z];
            }
            #pragma unroll
            for (int s = 0; s < 4; ++s) {
                unsigned m8 = (mg >> (8 * s)) & 0xFFu;
                if (m8) {
                    double d0 = (double)wc[s*4+0], d1 = (double)wc[s*4+1];
                    double d2 = (double)wc[s*4+2], d3 = (double)wc[s*4+3];
                    #pragma unroll
                    for (int b = 0; b < 8; ++b) if ((m8 >> b) & 1u) {
                        h1r[0 * 8 + b] += d0; h1r[1 * 8 + b] += d1;
                        h1r[2 * 8 + b] += d2; h1r[3 * 8 + b] += d3;
                    }
                }
            }
            #pragma unroll
            for (int z = 0; z < 16; ++z) wc[z] = wn[z];
        }
    }
    // part 2: s2 @ W2
    {
        const unsigned* s2u = (const unsigned*)s2msk;
        unsigned mwn = s2u[0];
        float wc[16];
        #pragma unroll
        for (int s = 0; s < 4; ++s) {
            const float* q = W2 + (size_t)s * 1024 + tid;
            wc[s*4+0] = q[0]; wc[s*4+1] = q[256]; wc[s*4+2] = q[512]; wc[s*4+3] = q[768];
        }
        for (int g = 0; g < 128; ++g) {
            unsigned mg = (unsigned)__builtin_amdgcn_readfirstlane((int)mwn);
            if (g + 1 < 128) mwn = s2u[g + 1];
            float wn[16];
            if (g + 1 < 128) {
                #pragma unroll
                for (int s = 0; s < 4; ++s) {
                    const float* q = W2 + (size_t)(4 * (g + 1) + s) * 1024 + tid;
                    wn[s*4+0] = q[0]; wn[s*4+1] = q[256]; wn[s*4+2] = q[512]; wn[s*4+3] = q[768];
                }
            } else {
                #pragma unroll
                for (int z = 0; z < 16; ++z) wn[z] = wc[z];
            }
            #pragma unroll
            for (int s = 0; s < 4; ++s) {
                unsigned m8 = (mg >> (8 * s)) & 0xFFu;
                if (m8) {
                    double d0 = (double)wc[s*4+0], d1 = (double)wc[s*4+1];
                    double d2 = (double)wc[s*4+2], d3 = (double)wc[s*4+3];
                    #pragma unroll
                    for (int b = 0; b < 8; ++b) if ((m8 >> b) & 1u) {
                        h1r[0 * 8 + b] += d0; h1r[1 * 8 + b] += d1;
                        h1r[2 * 8 + b] += d2; h1r[3 * 8 + b] += d3;
                    }
                }
            }
            #pragma unroll
            for (int z = 0; z < 16; ++z) wc[z] = wn[z];
        }
    }
    // part 3: s1 @ W2^T
    {
        const unsigned* s1u = (const unsigned*)s1msk;
        unsigned mwn = s1u[0];
        float wc[8];
        #pragma unroll
        for (int s = 0; s < 4; ++s) {
            const float* q = W2Tf + (size_t)s * 512 + tid;
            wc[s*2+0] = q[0]; wc[s*2+1] = q[256];
        }
        for (int g = 0; g < 256; ++g) {
            unsigned mg = (unsigned)__builtin_amdgcn_readfirstlane((int)mwn);
            if (g + 1 < 256) mwn = s1u[g + 1];
            float wn[8];
            if (g + 1 < 256) {
                #pragma unroll
                for (int s = 0; s < 4; ++s) {
                    const float* q = W2Tf + (size_t)(4 * (g + 1) + s) * 512 + tid;
                    wn[s*2+0] = q[0]; wn[s*2+1] = q[256];
                }
            } else {
                #pragma unroll
                for (int z = 0; z < 8; ++z) wn[z] = wc[z];
            }
            #pragma unroll
            for (int s = 0; s < 4; ++s) {
                unsigned m8 = (mg >> (8 * s)) & 0xFFu;
                if (m8) {
                    double d0 = (double)wc[s*2+0], d1 = (double)wc[s*2+1];
                    #pragma unroll
                    for (int b = 0; b < 8; ++b) if ((m8 >> b) & 1u) {
                        h2r[0 * 8 + b] += d0; h2r[1 * 8 + b] += d1;
                    }
                }
            }
            #pragma unroll
            for (int z = 0; z < 8; ++z) wc[z] = wn[z];
        }
    }

    #pragma unroll
    for (int k = 0; k < 4; ++k)
        #pragma unroll
        for (int b = 0; b < 8; ++b)
            h1g[(size_t)(b0 + b) * 1024 + k * 256 + tid] = h1r[k * 8 + b];
    #pragma unroll
    for (int k = 0; k < 2; ++k)
        #pragma unroll
        for (int b = 0; b < 8; ++b)
            h2g[(size_t)(b0 + b) * 512 + k * 256 + tid] = h2r[k * 8 + b];
}

// ---------------- Gibbs chain: 2 waves per batch row, wx register-resident ----------------

// one decision step: lane J's compare bit decides unit at step t0+J; all lanes
// apply the coupling wx[J][lane] to their running g. Pure VALU/SALU.
#define GSTEP(J, C) { \
    unsigned long long m_ = __ballot(g > thc); \
    int a_ = (int)((m_ >> (J)) & 1ull); \
    int o_ = (int)((OLD >> (J)) & 1ull); \
    A |= ((unsigned long long)(unsigned)a_) << (J); \
    g = fma((double)(a_ - o_), (double)(C), g); }

#define GSTEP4(K, X) GSTEP(4*(K)+0, (X).x) GSTEP(4*(K)+1, (X).y) \
                     GSTEP(4*(K)+2, (X).z) GSTEP(4*(K)+3, (X).w)

__global__ __launch_bounds__(128, 2) void gibbs(
    const double* __restrict__ TH, const int* __restrict__ ids,
    const float* __restrict__ WHf, const float* __restrict__ WOf,
    const float* __restrict__ WXT4,
    const int* __restrict__ pos2, const int* __restrict__ posB,
    const double* __restrict__ h1g, const double* __restrict__ h2g,
    const float* __restrict__ s1i, const float* __restrict__ s2i,
    float* __restrict__ out)
{
    const int lane = threadIdx.x & 63;
    const int wid  = threadIdx.x >> 6;     // 0: h1-owner, 1: h2-owner
    const int b = blockIdx.x;

    __shared__ double fld[1536];
    __shared__ unsigned long long act[N_WIN];
    __shared__ unsigned long long sb[24];

    double hr[16];
    if (wid == 0) {
        #pragma unroll
        for (int k = 0; k < 16; ++k)
            hr[k] = __builtin_nontemporal_load(&h1g[(size_t)b * 1024 + k * 64 + lane]);
        #pragma unroll
        for (int k = 0; k < 16; ++k) {
            unsigned long long m =
                __ballot(__builtin_nontemporal_load(&s1i[(size_t)b * 1024 + k * 64 + lane]) != 0.0f);
            if (lane == 0) sb[k] = m;
        }
    } else {
        #pragma unroll
        for (int k = 0; k < 8; ++k)
            hr[k] = __builtin_nontemporal_load(&h2g[(size_t)b * 512 + k * 64 + lane]);
        #pragma unroll
        for (int k = 0; k < 8; ++k) {
            unsigned long long m =
                __ballot(__builtin_nontemporal_load(&s2i[(size_t)b * 512 + k * 64 + lane]) != 0.0f);
            if (lane == 0) sb[16 + k] = m;
        }
    }

    int idw = ids[lane];
    double thc = __builtin_nontemporal_load(&TH[(size_t)b * 3072 + lane]);
    int p2c = 0;

    for (int w = 0; w < N_WIN; ++w) {
        const int t0 = w * 64;

        // load whole window's couplings into registers (coalesced float4 x16)
        const float4* wxg = (const float4*)WXT4 + ((size_t)w << 10) + lane;
        float4 x0  = wxg[0],   x1  = wxg[64],  x2  = wxg[128], x3  = wxg[192];
        float4 x4  = wxg[256], x5  = wxg[320], x6  = wxg[384], x7  = wxg[448];
        float4 x8  = wxg[512], x9  = wxg[576], x10 = wxg[640], x11 = wxg[704];
        float4 x12 = wxg[768], x13 = wxg[832], x14 = wxg[896], x15 = wxg[960];

        // mirror own fields to LDS
        if (wid == 0) {
            #pragma unroll
            for (int k = 0; k < 16; ++k) fld[k * 64 + lane] = hr[k];
        } else {
            #pragma unroll
            for (int k = 0; k < 8; ++k) fld[1024 + k * 64 + lane] = hr[k];
        }
        __syncthreads();
        double g = fld[idw];

        // old state (identical in both waves)
        int oldb;
        if (w < 24) {
            unsigned long long sv = sb[idw >> 6];
            oldb = (int)((sv >> (idw & 63)) & 1ull);
        } else {
            unsigned long long av = act[p2c >> 6];
            oldb = (int)((av >> (p2c & 63)) & 1ull);
        }
        unsigned long long OLD  = __ballot(oldb != 0);
        unsigned long long TYPE = __ballot(idw >= N_H);

        // prefetch next window inputs (consumed next iteration)
        int idn = 0; double thn = 0.0; int p2n = 0;
        if (w + 1 < N_WIN) {
            idn = ids[t0 + 64 + lane];
            thn = __builtin_nontemporal_load(&TH[(size_t)b * 3072 + t0 + 64 + lane]);
            if (w + 1 >= 24) p2n = pos2[(w - 23) * 64 + lane];
        }

        // serial decision loop -- pure ALU, fully unrolled
        unsigned long long A = 0;
        GSTEP4(0, x0)   GSTEP4(1, x1)   GSTEP4(2, x2)   GSTEP4(3, x3)
        GSTEP4(4, x4)   GSTEP4(5, x5)   GSTEP4(6, x6)   GSTEP4(7, x7)
        GSTEP4(8, x8)   GSTEP4(9, x9)   GSTEP4(10, x10) GSTEP4(11, x11)
        GSTEP4(12, x12) GSTEP4(13, x13) GSTEP4(14, x14) GSTEP4(15, x15)

        if (wid == 0 && lane == 0) act[w] = A;
        __syncthreads();   // fld gathers + act write complete before apply / next mirror

        // apply own-layer flips, depth-2 pipelined row loads
        if (wid == 0) {
            unsigned long long CC = (A ^ OLD) & TYPE;     // output-unit flips -> h1
            int j0 = -1, j1 = -1;
            float4 r00, r01, r02, r03, r10, r11, r12, r13;
            if (CC) {
                j0 = __builtin_ctzll(CC); CC &= CC - 1;
                int n = __builtin_amdgcn_readlane(idw, j0);
                const float4* p = (const float4*)(WOf + ((size_t)(n - N_H) << 10)) + (lane << 2);
                r00 = p[0]; r01 = p[1]; r02 = p[2]; r03 = p[3];
            }
            if (CC) {
                j1 = __builtin_ctzll(CC); CC &= CC - 1;
                int n = __builtin_amdgcn_readlane(idw, j1);
                const float4* p = (const float4*)(WOf + ((size_t)(n - N_H) << 10)) + (lane << 2);
                r10 = p[0]; r11 = p[1]; r12 = p[2]; r13 = p[3];
            }
            while (j0 >= 0) {
                double sd = ((A >> j0) & 1ull) ? 1.0 : -1.0;
                hr[0]  = fma(sd, (double)r00.x, hr[0]);
                hr[1]  = fma(sd, (double)r00.y, hr[1]);
                hr[2]  = fma(sd, (double)r00.z, hr[2]);
                hr[3]  = fma(sd, (double)r00.w, hr[3]);
                hr[4]  = fma(sd, (double)r01.x, hr[4]);
                hr[5]  = fma(sd, (double)r01.y, hr[5]);
                hr[6]  = fma(sd, (double)r01.z, hr[6]);
                hr[7]  = fma(sd, (double)r01.w, hr[7]);
                hr[8]  = fma(sd, (double)r02.x, hr[8]);
                hr[9]  = fma(sd, (double)r02.y, hr[9]);
                hr[10] = fma(sd, (double)r02.z, hr[10]);
                hr[11] = fma(sd, (double)r02.w, hr[11]);
                hr[12] = fma(sd, (double)r03.x, hr[12]);
                hr[13] = fma(sd, (double)r03.y, hr[13]);
                hr[14] = fma(sd, (double)r03.z, hr[14]);
                hr[15] = fma(sd, (double)r03.w, hr[15]);
                j0 = j1; r00 = r10; r01 = r11; r02 = r12; r03 = r13;
                j1 = -1;
                if (CC) {
                    j1 = __builtin_ctzll(CC); CC &= CC - 1;
                    int n = __builtin_amdgcn_readlane(idw, j1);
                    const float4* p = (const float4*)(WOf + ((size_t)(n - N_H) << 10)) + (lane << 2);
                    r10 = p[0]; r11 = p[1]; r12 = p[2]; r13 = p[3];
                }
            }
        } else {
            unsigned long long CC = (A ^ OLD) & ~TYPE;    // hidden-unit flips -> h2
            int j0 = -1, j1 = -1;
            float4 r00, r01, r10, r11;
            if (CC) {
                j0 = __builtin_ctzll(CC); CC &= CC - 1;
                int n = __builtin_amdgcn_readlane(idw, j0);
                const float4* p = (const float4*)(WHf + ((size_t)n << 9)) + (lane << 1);
                r00 = p[0]; r01 = p[1];
            }
            if (CC) {
                j1 = __builtin_ctzll(CC); CC &= CC - 1;
                int n = __builtin_amdgcn_readlane(idw, j1);
                const float4* p = (const float4*)(WHf + ((size_t)n << 9)) + (lane << 1);
                r10 = p[0]; r11 = p[1];
            }
            while (j0 >= 0) {
                double sd = ((A >> j0) & 1ull) ? 1.0 : -1.0;
                hr[0] = fma(sd, (double)r00.x, hr[0]);
                hr[1] = fma(sd, (double)r00.y, hr[1]);
                hr[2] = fma(sd, (double)r00.z, hr[2]);
                hr[3] = fma(sd, (double)r00.w, hr[3]);
                hr[4] = fma(sd, (double)r01.x, hr[4]);
                hr[5] = fma(sd, (double)r01.y, hr[5]);
                hr[6] = fma(sd, (double)r01.z, hr[6]);
                hr[7] = fma(sd, (double)r01.w, hr[7]);
                j0 = j1; r00 = r10; r01 = r11;
                j1 = -1;
                if (CC) {
                    j1 = __builtin_ctzll(CC); CC &= CC - 1;
                    int n = __builtin_amdgcn_readlane(idw, j1);
                    const float4* p = (const float4*)(WHf + ((size_t)n << 9)) + (lane << 1);
                    r10 = p[0]; r11 = p[1];
                }
            }
        }

        idw = idn; thc = thn; p2c = p2n;
    }

    __syncthreads();   // act fully written

    // epilogue: final states = sweep-2 decision bits (nontemporal stores)
    if (wid == 0) {
        #pragma unroll
        for (int k = 0; k < 16; ++k) {
            int p = posB[k * 64 + lane];
            unsigned long long av = act[24 + (p >> 6)];
            __builtin_nontemporal_store((float)((av >> (p & 63)) & 1ull),
                &out[(size_t)b * 2560 + 1024 + k * 64 + lane]);
        }
    } else {
        #pragma unroll
        for (int k = 0; k < 8; ++k) {
            int p = posB[1024 + k * 64 + lane];
            unsigned long long av = act[24 + (p >> 6)];
            __builtin_nontemporal_store((float)((av >> (p & 63)) & 1ull),
                &out[(size_t)b * 2560 + 2048 + k * 64 + lane]);
        }
    }
}

// ---------------- launch ----------------
extern "C" void kernel_launch(void* const* d_in, const int* in_sizes, int n_in,
                              void* d_out, int out_size, void* d_ws, size_t ws_size,
                              hipStream_t stream) {
    const float* x   = (const float*)d_in[0];
    const float* s1i = (const float*)d_in[1];
    const float* s2i = (const float*)d_in[2];
    const float* W1  = (const float*)d_in[3];
    const float* b1  = (const float*)d_in[4];
    const float* W2  = (const float*)d_in[5];
    const float* b2  = (const float*)d_in[6];
    const float* u   = (const float*)d_in[7];
    const int*   ids = (const int*)d_in[8];
    float* out = (float*)d_out;

    char* ws = (char*)d_ws;
    float*  W1T  = (float*) (ws);                               //  4 MB
    float*  W2Tf = (float*) (ws + ((size_t)4  << 20));          //  2 MB
    float*  WHf  = (float*) (ws + ((size_t)6  << 20));          //  2 MB
    float*  WOf  = (float*) (ws + ((size_t)8  << 20));          //  2 MB
    float*  WXT4 = (float*) (ws + ((size_t)10 << 20));          //  768 KB
    int*    posA = (int*)   (ws + ((size_t)11 << 20));          //  6 KB
    int*    posB = (int*)   (ws + ((size_t)11 << 20) + 8192);   //  6 KB
    int*    pos2 = (int*)   (ws + ((size_t)11 << 20) + 16384);  //  6 KB
    double* THd  = (double*)(ws + ((size_t)12 << 20));          // 48 MB
    double* h1g  = (double*)(ws + ((size_t)60 << 20));          // 16 MB
    double* h2g  = (double*)(ws + ((size_t)76 << 20));          //  8 MB (total 84 MB)

    hipLaunchKernelGGL(prep_w1t,  dim3(4096), dim3(256), 0, stream, W1, W1T);
    hipLaunchKernelGGL(prep_w2tf, dim3(2048), dim3(256), 0, stream, W2, W2Tf);
    hipLaunchKernelGGL(prep_whf,  dim3(2048), dim3(256), 0, stream, W2, WHf);
    hipLaunchKernelGGL(prep_wof,  dim3(2048), dim3(256), 0, stream, W2, WOf);
    hipLaunchKernelGGL(prep_wxt4, dim3(768),  dim3(256), 0, stream, W2, ids, WXT4);
    hipLaunchKernelGGL(prep_pos,  dim3(12),   dim3(256), 0, stream, ids, posA, posB);
    hipLaunchKernelGGL(prep_pos2, dim3(6),    dim3(256), 0, stream, ids, posA, pos2);
    hipLaunchKernelGGL(prep_th,   dim3(1536), dim3(256), 0, stream, u, THd);
    hipLaunchKernelGGL(copy_x,    dim3(2048), dim3(256), 0, stream, x, out);
    hipLaunchKernelGGL(init_fields, dim3(256), dim3(256), 0, stream,
                       x, s1i, s2i, W1T, W2, W2Tf, b1, b2, h1g, h2g);
    hipLaunchKernelGGL(gibbs, dim3(2048), dim3(128), 0, stream,
                       THd, ids, WHf, WOf, WXT4, pos2, posB, h1g, h2g, s1i, s2i, out);
}